// Round 3
// baseline (810.787 us; speedup 1.0000x reference)
//
#include <hip/hip_runtime.h>

typedef unsigned short u16;
typedef __attribute__((ext_vector_type(8))) short bf16x8;
typedef __attribute__((ext_vector_type(4))) float f32x4;

__device__ __forceinline__ u16 f2bf(float x){
  unsigned u = __builtin_bit_cast(unsigned, x);
  unsigned r = (u + 0x7FFFu + ((u >> 16) & 1u)) >> 16;   // RNE
  return (u16)r;
}
__device__ __forceinline__ float bf2f(u16 h){
  unsigned u = ((unsigned)h) << 16;
  return __builtin_bit_cast(float, u);
}

__device__ __forceinline__ void gld_lds16(const void* g, void* l){
  __builtin_amdgcn_global_load_lds((const __attribute__((address_space(1))) void*)g,
                                   (__attribute__((address_space(3))) void*)l,
                                   16, 0, 0);
}

// ---------------------------------------------------------------------------
// Weight transpose + bf16 hi/lo split:  W[K][1024] -> WT_hi/WT_lo [1024][Kpad]
// ---------------------------------------------------------------------------
__global__ void wconv_kernel(const float* __restrict__ W,
                             u16* __restrict__ Th, u16* __restrict__ Tl,
                             int K, int Kpad)
{
  __shared__ float t[32][33];
  int k0 = blockIdx.x * 32;
  int n0 = blockIdx.y * 32;
  int tx = threadIdx.x & 31, ty = threadIdx.x >> 5;
#pragma unroll
  for (int j = 0; j < 4; j++){
    int k = k0 + ty + j*8;
    float v = (k < K) ? W[(size_t)k*1024 + (n0 + tx)] : 0.f;
    t[ty + j*8][tx] = v;
  }
  __syncthreads();
#pragma unroll
  for (int j = 0; j < 4; j++){
    int n = n0 + ty + j*8;
    int k = k0 + tx;
    float v = t[tx][ty + j*8];
    u16 hi = f2bf(v);
    u16 lo = f2bf(v - bf2f(hi));
    size_t idx = (size_t)n*Kpad + k;
    Th[idx] = hi; Tl[idx] = lo;
  }
}

// ---------------------------------------------------------------------------
// feats: 729 bihom section products / kappa -> bf16 hi/lo, padded to 768.
// ---------------------------------------------------------------------------
__global__ void feats_kernel(const float* __restrict__ x,
                             u16* __restrict__ fh, u16* __restrict__ fl,
                             int row0)
{
  __shared__ float c[8][28];
  const int tid = threadIdx.x;
  const int lrow0 = blockIdx.x * 8;
  if (tid < 8){
    const float* xr = x + (size_t)(row0 + lrow0 + tid) * 18;
    float kk = 1.f;
#pragma unroll
    for (int f = 0; f < 3; f++){
      float xa = xr[3*f+0], xb = xr[3*f+1], xc = xr[3*f+2];
      float ya = xr[9+3*f+0], yb = xr[9+3*f+1], yc = xr[9+3*f+2];
      int bse = f * 9;
      c[tid][bse+0] = xa*xa + ya*ya;
      c[tid][bse+1] = xa*xb + ya*yb;
      c[tid][bse+2] = xa*xc + ya*yc;
      c[tid][bse+3] = xb*xb + yb*yb;
      c[tid][bse+4] = xb*xc + yb*yc;
      c[tid][bse+5] = xc*xc + yc*yc;
      c[tid][bse+6] = xa*yb - xb*ya;
      c[tid][bse+7] = xa*yc - xc*ya;
      c[tid][bse+8] = xb*yc - xc*yb;
      kk *= (xa*xa+ya*ya + xb*xb+yb*yb + xc*xc+yc*yc);
    }
    c[tid][27] = 1.f / kk;
  }
  __syncthreads();
#pragma unroll 1
  for (int jj = 0; jj < 24; jj++){               // 8 rows * 768 = 6144 = 24*256
    int idx = jj * 256 + tid;
    int rl = idx / 768;
    int o  = idx - rl * 768;
    const float* cc = c[rl];
    float v = 0.f;
    if (o < 729){
      int i12, j; float sgn; bool useR, jr2;
      if (o < 270)      { i12 = o/6;            j = o - i12*6;        sgn =  1.f; useR = true;  jr2 = true;  }
      else if (o < 378) { int t = o-270; i12 = t/3; j = t - i12*3;    sgn = -1.f; useR = false; jr2 = false; }
      else if (o < 513) { int t = o-378; i12 = t/3; j = t - i12*3;    sgn =  1.f; useR = true;  jr2 = false; }
      else              { int t = o-513; i12 = t/6; j = t - i12*6;    sgn = -1.f; useR = false; jr2 = true;  }
      float v12;
      if (useR){
        if (i12 < 36) v12 = cc[i12/6] * cc[9 + i12%6];
        else { int u = i12 - 36; v12 = -(cc[6 + u/3] * cc[15 + u%3]); }
      } else {
        if (i12 < 18) v12 = cc[i12/3] * cc[15 + i12%3];
        else { int u = i12 - 18; v12 = -(cc[6 + u/6] * cc[9 + u%6]); }
      }
      float f2 = jr2 ? cc[18 + j] : cc[24 + j];
      v = sgn * v12 * f2 * cc[27];
    }
    u16 hi = f2bf(v);
    u16 lo = f2bf(v - bf2f(hi));
    size_t oi = (size_t)lrow0 * 768 + idx;
    fh[oi] = hi; fl[oi] = lo;
  }
}

// ---------------------------------------------------------------------------
// Dual-tower GEMM, bf16x2 split precision (3 passes), 256x128 tile, BK=32,
// 512 threads (8 waves 4x2), 3-stage LDS pipeline with counted vmcnt waits
// (never 0 in main loop) + raw s_barrier. XCD-swizzled 1D grid.
// nb 0..7 -> tower a cols, nb 8..15 -> tower b cols.
// MODE 0: epilogue (acc+bias)^2 -> Ohi/Olo bf16 pair  (layer 1)
// MODE 1: epilogue (acc+bias)^2 * W3[col], block-col reduce -> partial  (layer 2)
//
// Dynamic LDS layout (u16 units):
//   sA: [3][2][256][32]  buf*16384 + h*8192 + row*32
//   sB: [3][2][128][32]  buf*8192  + h*4096 + row*32
//   rowsum: float[2][256]
// ---------------------------------------------------------------------------
#define GEMM_SMEM_BYTES ((3*2*256*32 + 3*2*128*32)*2 + 2*256*4)

#define STAGE(BUF) do{ \
    u16* _a = sA + (BUF)*16384; u16* _b = sB + (BUF)*8192; \
    gld_lds16(gAh0, _a + wave*1024);        gld_lds16(gAh1, _a + wave*1024 + 512); \
    gld_lds16(gAl0, _a + 8192 + wave*1024); gld_lds16(gAl1, _a + 8192 + wave*1024 + 512); \
    gld_lds16(gBh0, _b + wave*512);         gld_lds16(gBl0, _b + 4096 + wave*512); \
    gAh0 += 32; gAh1 += 32; gAl0 += 32; gAl1 += 32; gBh0 += 32; gBl0 += 32; \
  }while(0)

#define COMPUTE(BUF) do{ \
    const u16* pA = sA + (BUF)*16384; \
    const u16* pB = sB + (BUF)*8192; \
    bf16x8 ah_[4], bh_[4], al_[4], bl_[4]; \
    _Pragma("unroll") for (int m_ = 0; m_ < 4; m_++) ah_[m_] = *(const bf16x8*)(pA + (wm*64 + m_*16 + r16)*32 + slot); \
    _Pragma("unroll") for (int n_ = 0; n_ < 4; n_++) bh_[n_] = *(const bf16x8*)(pB + (wn*64 + n_*16 + r16)*32 + slot); \
    _Pragma("unroll") for (int m_ = 0; m_ < 4; m_++) \
      _Pragma("unroll") for (int n_ = 0; n_ < 4; n_++) \
        acc[m_][n_] = __builtin_amdgcn_mfma_f32_16x16x32_bf16(ah_[m_], bh_[n_], acc[m_][n_], 0, 0, 0); \
    _Pragma("unroll") for (int m_ = 0; m_ < 4; m_++) al_[m_] = *(const bf16x8*)(pA + 8192 + (wm*64 + m_*16 + r16)*32 + slot); \
    _Pragma("unroll") for (int m_ = 0; m_ < 4; m_++) \
      _Pragma("unroll") for (int n_ = 0; n_ < 4; n_++) \
        acc[m_][n_] = __builtin_amdgcn_mfma_f32_16x16x32_bf16(al_[m_], bh_[n_], acc[m_][n_], 0, 0, 0); \
    _Pragma("unroll") for (int n_ = 0; n_ < 4; n_++) bl_[n_] = *(const bf16x8*)(pB + 4096 + (wn*64 + n_*16 + r16)*32 + slot); \
    _Pragma("unroll") for (int m_ = 0; m_ < 4; m_++) \
      _Pragma("unroll") for (int n_ = 0; n_ < 4; n_++) \
        acc[m_][n_] = __builtin_amdgcn_mfma_f32_16x16x32_bf16(ah_[m_], bl_[n_], acc[m_][n_], 0, 0, 0); \
  }while(0)

template<int MODE>
__global__ __launch_bounds__(512, 1) void gemm_k(
    const u16* __restrict__ Aha, const u16* __restrict__ Ala,
    const u16* __restrict__ Ahb, const u16* __restrict__ Alb,
    const u16* __restrict__ Bha, const u16* __restrict__ Bla,
    const u16* __restrict__ Bhb, const u16* __restrict__ Blb,
    const float* __restrict__ biasa, const float* __restrict__ biasb,
    u16* __restrict__ Oha, u16* __restrict__ Ola,
    u16* __restrict__ Ohb, u16* __restrict__ Olb,
    const float* __restrict__ W3a_, const float* __restrict__ W3b_,
    float* __restrict__ Pa, float* __restrict__ Pb, int Pstride,
    int K)
{
  extern __shared__ __align__(16) u16 smem[];
  u16* sA = smem;                          // 3*2*256*32 = 49152 u16
  u16* sB = smem + 49152;                  // 3*2*128*32 = 24576 u16
  float* rowsum = (float*)(smem + 49152 + 24576);   // [2][256]

  // bijective XCD swizzle (nwg = 16*MB, always % 8 == 0)
  const int nwg = gridDim.x;
  const int qq = nwg >> 3;
  const int wg = (blockIdx.x & 7) * qq + (blockIdx.x >> 3);
  const int nb = wg & 15;
  const int mb = wg >> 4;
  const int tower = nb >> 3, cnb = nb & 7;

  const u16* Ahi = tower ? Ahb : Aha;
  const u16* Alo = tower ? Alb : Ala;
  const u16* Bhi = tower ? Bhb : Bha;
  const u16* Blo = tower ? Blb : Bla;
  const float* bias = tower ? biasb : biasa;

  const int tid = threadIdx.x;
  const int wave = tid >> 6, lane = tid & 63;
  const int wm = wave >> 1, wn = wave & 1;    // 4 row-waves x 2 col-waves

  // staging addressing (rule-21 pair: inverse-swizzled global source, linear LDS dest)
  const int l4 = lane >> 2, ls = lane & 3;
  const int fsw  = (l4 >> 1) & 3;
  const int koff = ((ls ^ fsw) << 3);

  const u16* gAh0 = Ahi + (size_t)(mb*256 + wave*32 + l4) * K + koff;
  const u16* gAh1 = gAh0 + (size_t)16 * K;
  const u16* gAl0 = Alo + (size_t)(mb*256 + wave*32 + l4) * K + koff;
  const u16* gAl1 = gAl0 + (size_t)16 * K;
  const u16* gBh0 = Bhi + (size_t)(cnb*128 + wave*16 + l4) * K + koff;
  const u16* gBl0 = Blo + (size_t)(cnb*128 + wave*16 + l4) * K + koff;

  // fragment addressing (swizzled ds_read)
  const int r16 = lane & 15, g = lane >> 4;
  const int fr   = (r16 >> 1) & 3;
  const int slot = ((g ^ fr) << 3);

  f32x4 acc[4][4];
#pragma unroll
  for (int m = 0; m < 4; m++)
#pragma unroll
    for (int n = 0; n < 4; n++)
      acc[m][n] = (f32x4){0.f, 0.f, 0.f, 0.f};

  const int NT = K >> 5;          // 24 or 32, always >= 3
  STAGE(0);
  STAGE(1);                        // 12 loads outstanding per wave

#pragma unroll 1
  for (int t = 0; t < NT; ++t){
    // complete tile t's loads (6 of ours remain beyond it in steady state)
    if (t < NT - 1){
      asm volatile("s_waitcnt vmcnt(6)\n\ts_barrier" ::: "memory");
    } else {
      asm volatile("s_waitcnt vmcnt(0)\n\ts_barrier" ::: "memory");
    }
    int sb = t + 2;
    if (sb < NT){
      int sbuf = sb - (sb >= 3 ? 3 : 0); sbuf = sb % 3;
      STAGE(sbuf);
    }
    int cbuf = t % 3;
    COMPUTE(cbuf);
  }

  if constexpr (MODE == 0){
    u16* Oh = tower ? Ohb : Oha;
    u16* Ol = tower ? Olb : Ola;
#pragma unroll
    for (int n = 0; n < 4; n++){
      int col = cnb*128 + wn*64 + n*16 + r16;
      float bv = bias[col];
#pragma unroll
      for (int m = 0; m < 4; m++){
        int rbase = mb*256 + wm*64 + m*16 + g*4;
#pragma unroll
        for (int q = 0; q < 4; q++){
          float val = acc[m][n][q] + bv;
          val = val * val;
          u16 hi = f2bf(val);
          u16 lo = f2bf(val - bf2f(hi));
          size_t oi = (size_t)(rbase + q) * 1024 + col;
          Oh[oi] = hi; Ol[oi] = lo;
        }
      }
    }
  } else {
    const float* W3 = tower ? W3b_ : W3a_;
    float w3v[4], bv[4];
#pragma unroll
    for (int n = 0; n < 4; n++){
      int col = cnb*128 + wn*64 + n*16 + r16;
      w3v[n] = W3[col];
      bv[n]  = bias[col];
    }
    float rp[4][4];
#pragma unroll
    for (int m = 0; m < 4; m++)
#pragma unroll
      for (int q = 0; q < 4; q++)
        rp[m][q] = 0.f;
#pragma unroll
    for (int m = 0; m < 4; m++)
#pragma unroll
      for (int n = 0; n < 4; n++)
#pragma unroll
        for (int q = 0; q < 4; q++){
          float v = acc[m][n][q] + bv[n];
          rp[m][q] += v * v * w3v[n];
        }
#pragma unroll
    for (int m = 0; m < 4; m++)
#pragma unroll
      for (int q = 0; q < 4; q++){
        float s = rp[m][q];
        s += __shfl_xor(s, 1); s += __shfl_xor(s, 2);
        s += __shfl_xor(s, 4); s += __shfl_xor(s, 8);
        rp[m][q] = s;
      }
    if (r16 == 0){
#pragma unroll
      for (int m = 0; m < 4; m++)
#pragma unroll
        for (int q = 0; q < 4; q++)
          rowsum[wn*256 + wm*64 + m*16 + g*4 + q] = rp[m][q];
    }
    __syncthreads();
    if (tid < 256){
      float s = rowsum[tid] + rowsum[256 + tid];
      float* P = tower ? Pb : Pa;
      P[(size_t)cnb * Pstride + mb*256 + tid] = s;
    }
  }
}

// ---------------------------------------------------------------------------
// finalize: a3 = b3 + sum_j partial[j][row]; out = clip(2log|a3a|*Wfa - ..b..)
// ---------------------------------------------------------------------------
__global__ void finalize_kernel(const float* __restrict__ Pa, const float* __restrict__ Pb,
                                int Pstride,
                                const float* __restrict__ b3a, const float* __restrict__ Wfa,
                                const float* __restrict__ b3b, const float* __restrict__ Wfb,
                                float* __restrict__ out, int row0, int Rc)
{
  int r = blockIdx.x * 256 + threadIdx.x;
  if (r >= Rc) return;
  float sa = b3a[0], sb = b3b[0];
#pragma unroll
  for (int j = 0; j < 8; j++){
    sa += Pa[(size_t)j * Pstride + r];
    sb += Pb[(size_t)j * Pstride + r];
  }
  float ta = 2.f * logf(fabsf(sa)) * Wfa[0];
  float tb = 2.f * logf(fabsf(sb)) * Wfb[0];
  float o = ta - tb;
  o = fminf(fmaxf(o, -1000000.f), 1000000.f);
  out[row0 + r] = o;
}

// ---------------------------------------------------------------------------
static inline size_t align256(size_t v){ return (v + 255) & ~(size_t)255; }

extern "C" void kernel_launch(void* const* d_in, const int* in_sizes, int n_in,
                              void* d_out, int out_size, void* d_ws, size_t ws_size,
                              hipStream_t stream)
{
  (void)n_in; (void)out_size;
  const float* x   = (const float*)d_in[0];
  const float* W1a = (const float*)d_in[1];
  const float* b1a = (const float*)d_in[2];
  const float* W2a = (const float*)d_in[3];
  const float* b2a = (const float*)d_in[4];
  const float* W3a = (const float*)d_in[5];
  const float* b3a = (const float*)d_in[6];
  const float* Wfa = (const float*)d_in[7];
  const float* W1b = (const float*)d_in[8];
  const float* b1b = (const float*)d_in[9];
  const float* W2b = (const float*)d_in[10];
  const float* b2b = (const float*)d_in[11];
  const float* W3b = (const float*)d_in[12];
  const float* b3b = (const float*)d_in[13];
  const float* Wfb = (const float*)d_in[14];
  float* out = (float*)d_out;

  const int B  = in_sizes[0] / 18;
  const int K1 = 768;
  const int K2 = 1024;

  // allow >64KB dynamic LDS (deterministic, non-stream op)
  hipFuncSetAttribute((const void*)gemm_k<0>,
                      hipFuncAttributeMaxDynamicSharedMemorySize, GEMM_SMEM_BYTES);
  hipFuncSetAttribute((const void*)gemm_k<1>,
                      hipFuncAttributeMaxDynamicSharedMemorySize, GEMM_SMEM_BYTES);

  char* base = (char*)d_ws;
  size_t off = 0;
  auto carve = [&](size_t bytes) -> char* {
    off = align256(off);
    char* p = base + off;
    off += bytes;
    return p;
  };

  u16* wt1ah = (u16*)carve((size_t)1024 * K1 * 2);
  u16* wt1al = (u16*)carve((size_t)1024 * K1 * 2);
  u16* wt2ah = (u16*)carve((size_t)1024 * K2 * 2);
  u16* wt2al = (u16*)carve((size_t)1024 * K2 * 2);
  u16* wt1bh = (u16*)carve((size_t)1024 * K1 * 2);
  u16* wt1bl = (u16*)carve((size_t)1024 * K1 * 2);
  u16* wt2bh = (u16*)carve((size_t)1024 * K2 * 2);
  u16* wt2bl = (u16*)carve((size_t)1024 * K2 * 2);

  size_t fixed = align256(off);
  const long long per_row = (long long)K1*4 + 8192 + 64;
  long long avail = (long long)ws_size - (long long)fixed - 8192;
  long long rmax = avail > 0 ? avail / per_row : 0;
  int R = (int)((rmax / 256) * 256);
  if (R > B) R = B;
  if (R < 256) R = 256;

  u16* fh   = (u16*)carve((size_t)R * K1 * 2);
  u16* fl   = (u16*)carve((size_t)R * K1 * 2);
  u16* h1ah = (u16*)carve((size_t)R * 1024 * 2);
  u16* h1al = (u16*)carve((size_t)R * 1024 * 2);
  u16* h1bh = (u16*)carve((size_t)R * 1024 * 2);
  u16* h1bl = (u16*)carve((size_t)R * 1024 * 2);
  float* pa = (float*)carve((size_t)8 * R * 4);
  float* pb = (float*)carve((size_t)8 * R * 4);

  wconv_kernel<<<dim3(K1/32, 32), 256, 0, stream>>>(W1a, wt1ah, wt1al, 729,  K1);
  wconv_kernel<<<dim3(K2/32, 32), 256, 0, stream>>>(W2a, wt2ah, wt2al, 1024, K2);
  wconv_kernel<<<dim3(K1/32, 32), 256, 0, stream>>>(W1b, wt1bh, wt1bl, 729,  K1);
  wconv_kernel<<<dim3(K2/32, 32), 256, 0, stream>>>(W2b, wt2bh, wt2bl, 1024, K2);

  for (int row0 = 0; row0 < B; row0 += R){
    int Rc = B - row0; if (Rc > R) Rc = R;
    int MB = Rc / 256;
    feats_kernel<<<Rc/8, 256, 0, stream>>>(x, fh, fl, row0);
    gemm_k<0><<<dim3(16*MB), 512, GEMM_SMEM_BYTES, stream>>>(
        fh, fl, fh, fl,
        wt1ah, wt1al, wt1bh, wt1bl,
        b1a, b1b,
        h1ah, h1al, h1bh, h1bl,
        nullptr, nullptr, nullptr, nullptr, 0, K1);
    gemm_k<1><<<dim3(16*MB), 512, GEMM_SMEM_BYTES, stream>>>(
        h1ah, h1al, h1bh, h1bl,
        wt2ah, wt2al, wt2bh, wt2bl,
        b2a, b2b,
        nullptr, nullptr, nullptr, nullptr,
        W3a, W3b, pa, pb, R, K2);
    finalize_kernel<<<(Rc + 255)/256, 256, 0, stream>>>(pa, pb, R, b3a, Wfa, b3b, Wfb,
                                                        out, row0, Rc);
  }
}